// Round 2
// 421.803 us; speedup vs baseline: 1.0048x; 1.0048x over previous
//
#include <hip/hip_runtime.h>

// GCN forward: conv1(GEMM + sym-norm agg) -> BN -> PReLU -> conv2(GEMM + agg)
// N=100000, E=1600000, DIN=128, 2H=128, H=64. fp32 in/out.
//
// R5 = R4 with compile fix (__builtin_nontemporal_store needs ext_vector, not
// HIP_vector_type<float,2>).
// R4 changes vs R3 (424 us):
//  - gemm1/gemm2 rewritten on MFMA (16x16x32 bf16) with 3-term split precision
//    (x_hi@W_hi + x_lo@W_hi + x_hi@W_lo): fp32-accurate to ~2^-16 rel, moves
//    GEMMs from the 157 TF fp32 VALU pipe to the matrix pipe (memory-bound).
//  - bnfinal fused into gemm2 (per-block redundant scale/shift from bnacc).
//  - GEMM epilogues pre-scale rows by dinv -> agg kernels drop the per-edge
//    dinv[src] gather + dependent fma.
//  - agg1/agg2 unrolled 8-deep; z/out stores non-temporal (keep gather table
//    resident in L2).

#define DIN 128
#define F1  128   // 2H
#define F2  64    // H
#define BN_EPS 1e-5f
#define NODE_BSHIFT 8          // 256 nodes per bucket
#define NODE_BMASK  255
#define CHUNK 8192             // edges per binpass block

typedef __attribute__((ext_vector_type(8))) short bf16x8;
typedef __attribute__((ext_vector_type(4))) float f32x4;
typedef __attribute__((ext_vector_type(2))) float f32x2;

__device__ __forceinline__ unsigned short f2bf(float f) {
    unsigned int u = __float_as_uint(f);
    u = u + 0x7fffu + ((u >> 16) & 1u);   // RNE
    return (unsigned short)(u >> 16);
}
__device__ __forceinline__ float bf2f(unsigned short u) { return __uint_as_float((unsigned int)u << 16); }
__device__ __forceinline__ float bf_lo(unsigned int v) { return __uint_as_float(v << 16); }
__device__ __forceinline__ float bf_hi(unsigned int v) { return __uint_as_float(v & 0xffff0000u); }

// ---------------- graph build (unchanged from R3) ----------------

__global__ __launch_bounds__(256) void hist_k(const int* __restrict__ dst,
                                              int* __restrict__ bucketcnt,
                                              int e, int nbuck) {
    __shared__ int lh[512];
    int t = threadIdx.x;
    for (int i = t; i < 512; i += 256) lh[i] = 0;
    __syncthreads();
    int base = blockIdx.x * CHUNK;
    int end = base + CHUNK; if (end > e) end = e;
    for (int i = base + t; i < end; i += 256)
        atomicAdd(&lh[dst[i] >> NODE_BSHIFT], 1);
    __syncthreads();
    for (int b = t; b < nbuck; b += 256) {
        int v = lh[b];
        if (v) atomicAdd(&bucketcnt[b], v);
    }
}

__global__ __launch_bounds__(512) void bscan_k(const int* __restrict__ bucketcnt,
                                               int* __restrict__ bucketbase,
                                               int* __restrict__ bucketcur,
                                               int* __restrict__ rowptr,
                                               int nbuck, int n, int e) {
    __shared__ int s[512];
    int t = threadIdx.x;
    int orig = (t < nbuck) ? bucketcnt[t] : 0;
    s[t] = orig;
    __syncthreads();
    int run = orig;
    for (int ofs = 1; ofs < 512; ofs <<= 1) {
        int y = (t >= ofs) ? s[t - ofs] : 0;
        __syncthreads();
        run += y;
        s[t] = run;
        __syncthreads();
    }
    if (t < nbuck) {
        int excl = run - orig;
        bucketbase[t] = excl;
        bucketcur[t] = excl;
    }
    if (t == 0) {
        bucketbase[nbuck] = e;
        rowptr[n] = e;
    }
}

__global__ __launch_bounds__(256) void binpass_k(const int* __restrict__ src,
                                                 const int* __restrict__ dst,
                                                 int* __restrict__ bucketcur,
                                                 int2* __restrict__ pairs, int e) {
    __shared__ int lh[512], lbase[512], lrank[512];
    int t = threadIdx.x;
    for (int i = t; i < 512; i += 256) { lh[i] = 0; lrank[i] = 0; }
    __syncthreads();
    int base = blockIdx.x * CHUNK;
    int end = base + CHUNK; if (end > e) end = e;
    for (int i = base + t; i < end; i += 256)
        atomicAdd(&lh[dst[i] >> NODE_BSHIFT], 1);
    __syncthreads();
    for (int b = t; b < 512; b += 256) {
        int v = lh[b];
        lbase[b] = v ? atomicAdd(&bucketcur[b], v) : 0;
    }
    __syncthreads();
    for (int i = base + t; i < end; i += 256) {
        int sv = src[i], dv = dst[i];
        int b = dv >> NODE_BSHIFT;
        int r = atomicAdd(&lrank[b], 1);
        pairs[lbase[b] + r] = make_int2(sv, dv);
    }
}

__global__ __launch_bounds__(256) void bucket_k(const int2* __restrict__ pairs,
                                                const int* __restrict__ bucketbase,
                                                float* __restrict__ dinv,
                                                int* __restrict__ rowptr,
                                                int* __restrict__ srcsorted, int n) {
    __shared__ int lh[256], loff[256], lrank[256];
    int b = blockIdx.x, t = threadIdx.x;
    int e0 = bucketbase[b], e1 = bucketbase[b + 1];
    lh[t] = 0;
    lrank[t] = 0;
    __syncthreads();
    for (int i = e0 + t; i < e1; i += 256)
        atomicAdd(&lh[pairs[i].y & NODE_BMASK], 1);
    __syncthreads();
    int deg = lh[t];
    int run = deg;
    for (int ofs = 1; ofs < 256; ofs <<= 1) {
        int y = (t >= ofs) ? lh[t - ofs] : 0;
        __syncthreads();
        run += y;
        lh[t] = run;
        __syncthreads();
    }
    loff[t] = run - deg;
    int node = (b << NODE_BSHIFT) + t;
    if (node < n) {
        dinv[node] = rsqrtf((float)(deg + 1));   // +1 self-loop
        rowptr[node] = e0 + (run - deg);
    }
    __syncthreads();
    for (int i = e0 + t; i < e1; i += 256) {
        int2 p = pairs[i];
        int lo = p.y & NODE_BMASK;
        int r = atomicAdd(&lrank[lo], 1);
        srcsorted[e0 + loff[lo] + r] = p.x;
    }
}

// ---- GEMM1 (MFMA): h'(bf16) = dinv * (x @ W1), split precision ----
// 128 rows/block, 512 threads (8 waves of 16 rows x 128 cols).

__global__ __launch_bounds__(512) void gemm1_k(const float* __restrict__ x,
                                               const float* __restrict__ W,
                                               const float* __restrict__ dinv,
                                               unsigned int* __restrict__ h, int n) {
    __shared__ unsigned short wh[128 * 128];   // W^T hi, [col][k], 16B-chunk XOR swizzle
    __shared__ unsigned short wl[128 * 128];   // W^T lo
    int t = threadIdx.x;
    // stage W1 [k=128][c=128] fp32 -> swizzled transposed bf16 hi/lo
    for (int i4 = t; i4 < 128 * 32; i4 += 512) {
        int k = i4 >> 5;
        int c0 = (i4 & 31) * 4;
        float4 v = ((const float4*)W)[i4];
        float vv[4] = {v.x, v.y, v.z, v.w};
#pragma unroll
        for (int j = 0; j < 4; j++) {
            int c = c0 + j;
            unsigned short hi = f2bf(vv[j]);
            unsigned short lo = f2bf(vv[j] - bf2f(hi));
            int addr = c * 128 + ((((k >> 3) ^ (c & 15))) << 3) + (k & 7);
            wh[addr] = hi;
            wl[addr] = lo;
        }
    }
    __syncthreads();

    int w = t >> 6, l = t & 63;
    int lr = l & 15, lg = l >> 4;
    int rowbase = blockIdx.x * 128;
    int arow = rowbase + w * 16 + lr;
    if (arow >= n) arow = n - 1;

    f32x4 acc[8];
#pragma unroll
    for (int nt = 0; nt < 8; nt++) acc[nt] = (f32x4)(0.0f);

#pragma unroll
    for (int ks = 0; ks < 4; ks++) {
        const float4* ap = (const float4*)(x + (size_t)arow * 128 + ks * 32 + lg * 8);
        float4 v0 = ap[0], v1 = ap[1];
        float vv[8] = {v0.x, v0.y, v0.z, v0.w, v1.x, v1.y, v1.z, v1.w};
        bf16x8 ah, al;
#pragma unroll
        for (int j = 0; j < 8; j++) {
            unsigned short hi = f2bf(vv[j]);
            ah[j] = (short)hi;
            al[j] = (short)f2bf(vv[j] - bf2f(hi));
        }
#pragma unroll
        for (int nt = 0; nt < 8; nt++) {
            int ao = (nt * 16 + lr) * 128 + (((4 * ks + lg) ^ lr) << 3);
            bf16x8 bh = *(const bf16x8*)&wh[ao];
            bf16x8 bl = *(const bf16x8*)&wl[ao];
            acc[nt] = __builtin_amdgcn_mfma_f32_16x16x32_bf16(ah, bh, acc[nt], 0, 0, 0);
            acc[nt] = __builtin_amdgcn_mfma_f32_16x16x32_bf16(al, bh, acc[nt], 0, 0, 0);
            acc[nt] = __builtin_amdgcn_mfma_f32_16x16x32_bf16(ah, bl, acc[nt], 0, 0, 0);
        }
    }
    __syncthreads();                       // all waves done reading W
    unsigned short* ob = wh;               // reuse as [128][128] bf16 bounce
#pragma unroll
    for (int r = 0; r < 4; r++) {
        int rl = w * 16 + lg * 4 + r;      // C row = (lane>>4)*4 + reg
        int grow = rowbase + rl;
        float di = dinv[grow < n ? grow : 0];
#pragma unroll
        for (int nt = 0; nt < 8; nt++)
            ob[rl * 128 + nt * 16 + lr] = f2bf(acc[nt][r] * di);
    }
    __syncthreads();
    const unsigned int* ob32 = (const unsigned int*)ob;
    for (int i = t; i < 128 * 64; i += 512) {
        int rl = i >> 6, cu = i & 63;
        int grow = rowbase + rl;
        if (grow < n) h[(size_t)grow * 64 + cu] = ob32[rl * 64 + cu];
    }
}

// -------- aggregation 1: z = dinv_d * (sum h'_s + h'_d) + b1 --------

__global__ __launch_bounds__(64) void agg1_k(const unsigned int* __restrict__ h,  // bf16x2, 64/row
                                             const float* __restrict__ dinv,
                                             const int* __restrict__ rowptr,
                                             const int* __restrict__ srcs,
                                             const float* __restrict__ b1,
                                             float* __restrict__ z, int n) {
    int nd = blockIdx.x;
    int f = threadIdx.x;  // bf16-pair index, 0..63
    float di = dinv[nd];
    unsigned int sv = h[(size_t)nd * 64 + f];
    float ax = bf_lo(sv);
    float ay = bf_hi(sv);
    int e = rowptr[nd], e1 = rowptr[nd + 1];
    for (; e + 8 <= e1; e += 8) {
        int s0 = srcs[e],     s1 = srcs[e + 1], s2 = srcs[e + 2], s3 = srcs[e + 3];
        int s4 = srcs[e + 4], s5 = srcs[e + 5], s6 = srcs[e + 6], s7 = srcs[e + 7];
        unsigned int v0 = h[(size_t)s0 * 64 + f];
        unsigned int v1 = h[(size_t)s1 * 64 + f];
        unsigned int v2 = h[(size_t)s2 * 64 + f];
        unsigned int v3 = h[(size_t)s3 * 64 + f];
        unsigned int v4 = h[(size_t)s4 * 64 + f];
        unsigned int v5 = h[(size_t)s5 * 64 + f];
        unsigned int v6 = h[(size_t)s6 * 64 + f];
        unsigned int v7 = h[(size_t)s7 * 64 + f];
        ax += bf_lo(v0) + bf_lo(v1) + bf_lo(v2) + bf_lo(v3);
        ay += bf_hi(v0) + bf_hi(v1) + bf_hi(v2) + bf_hi(v3);
        ax += bf_lo(v4) + bf_lo(v5) + bf_lo(v6) + bf_lo(v7);
        ay += bf_hi(v4) + bf_hi(v5) + bf_hi(v6) + bf_hi(v7);
    }
    for (; e < e1; e++) {
        unsigned int v = h[(size_t)srcs[e] * 64 + f];
        ax += bf_lo(v);
        ay += bf_hi(v);
    }
    float2 bb = ((const float2*)b1)[f];
    f32x2 o;
    o.x = fmaf(ax, di, bb.x);
    o.y = fmaf(ay, di, bb.y);
    __builtin_nontemporal_store(o, (f32x2*)z + (size_t)nd * 64 + f);
}

// ---------------- BatchNorm stats ----------------

__global__ __launch_bounds__(128) void bnstats_k(const float* __restrict__ z,
                                                 double* __restrict__ bnacc, int n) {
    int f = threadIdx.x;
    float s = 0.f, q = 0.f;
    for (int r = blockIdx.x; r < n; r += gridDim.x) {
        float v = z[(size_t)r * F1 + f];
        s += v;
        q = fmaf(v, v, q);
    }
    atomicAdd(&bnacc[f], (double)s);
    atomicAdd(&bnacc[F1 + f], (double)q);
}

// ---- GEMM2 (MFMA): h2'(bf16) = dinv * (prelu(bn(z)) @ W2), bnfinal fused ----
// 128 rows/block, 512 threads (8 waves of 16 rows x 64 cols).

__global__ __launch_bounds__(512) void gemm2_k(const float* __restrict__ z,
                                               const float* __restrict__ W,      // [128][64]
                                               const double* __restrict__ bnacc,
                                               const float* __restrict__ gamma,
                                               const float* __restrict__ beta,
                                               const float* __restrict__ prelu_a,
                                               const float* __restrict__ dinv,
                                               unsigned int* __restrict__ h2, int n) {
    __shared__ unsigned short wh[64 * 128];
    __shared__ unsigned short wl[64 * 128];
    __shared__ float lsc[128], lsh[128];
    int t = threadIdx.x;
    for (int i4 = t; i4 < 128 * 16; i4 += 512) {
        int k = i4 >> 4;
        int c0 = (i4 & 15) * 4;
        float4 v = ((const float4*)W)[i4];
        float vv[4] = {v.x, v.y, v.z, v.w};
#pragma unroll
        for (int j = 0; j < 4; j++) {
            int c = c0 + j;
            unsigned short hi = f2bf(vv[j]);
            unsigned short lo = f2bf(vv[j] - bf2f(hi));
            int addr = c * 128 + ((((k >> 3) ^ (c & 15))) << 3) + (k & 7);
            wh[addr] = hi;
            wl[addr] = lo;
        }
    }
    if (t < 128) {   // fused bnfinal
        double mean = bnacc[t] / n;
        double var = bnacc[128 + t] / n - mean * mean;
        float sc = gamma[t] * rsqrtf((float)var + BN_EPS);
        lsc[t] = sc;
        lsh[t] = beta[t] - (float)mean * sc;
    }
    __syncthreads();

    float pa = prelu_a[0];
    int w = t >> 6, l = t & 63;
    int lr = l & 15, lg = l >> 4;
    int rowbase = blockIdx.x * 128;
    int arow = rowbase + w * 16 + lr;
    if (arow >= n) arow = n - 1;

    f32x4 acc[4];
#pragma unroll
    for (int nt = 0; nt < 4; nt++) acc[nt] = (f32x4)(0.0f);

#pragma unroll
    for (int ks = 0; ks < 4; ks++) {
        const float4* ap = (const float4*)(z + (size_t)arow * 128 + ks * 32 + lg * 8);
        float4 v0 = ap[0], v1 = ap[1];
        const float4* sc4 = (const float4*)&lsc[ks * 32 + lg * 8];
        const float4* sh4 = (const float4*)&lsh[ks * 32 + lg * 8];
        float4 s0 = sc4[0], s1 = sc4[1];
        float4 t0 = sh4[0], t1 = sh4[1];
        float vv[8];
        vv[0] = fmaf(v0.x, s0.x, t0.x); vv[1] = fmaf(v0.y, s0.y, t0.y);
        vv[2] = fmaf(v0.z, s0.z, t0.z); vv[3] = fmaf(v0.w, s0.w, t0.w);
        vv[4] = fmaf(v1.x, s1.x, t1.x); vv[5] = fmaf(v1.y, s1.y, t1.y);
        vv[6] = fmaf(v1.z, s1.z, t1.z); vv[7] = fmaf(v1.w, s1.w, t1.w);
        bf16x8 ah, al;
#pragma unroll
        for (int j = 0; j < 8; j++) {
            float y = vv[j] >= 0.f ? vv[j] : pa * vv[j];
            unsigned short hi = f2bf(y);
            ah[j] = (short)hi;
            al[j] = (short)f2bf(y - bf2f(hi));
        }
#pragma unroll
        for (int nt = 0; nt < 4; nt++) {
            int ao = (nt * 16 + lr) * 128 + (((4 * ks + lg) ^ lr) << 3);
            bf16x8 bh = *(const bf16x8*)&wh[ao];
            bf16x8 bl = *(const bf16x8*)&wl[ao];
            acc[nt] = __builtin_amdgcn_mfma_f32_16x16x32_bf16(ah, bh, acc[nt], 0, 0, 0);
            acc[nt] = __builtin_amdgcn_mfma_f32_16x16x32_bf16(al, bh, acc[nt], 0, 0, 0);
            acc[nt] = __builtin_amdgcn_mfma_f32_16x16x32_bf16(ah, bl, acc[nt], 0, 0, 0);
        }
    }
    __syncthreads();
    unsigned short* ob = wh;   // reuse as [128][64] bf16 bounce
#pragma unroll
    for (int r = 0; r < 4; r++) {
        int rl = w * 16 + lg * 4 + r;
        int grow = rowbase + rl;
        float di = dinv[grow < n ? grow : 0];
#pragma unroll
        for (int nt = 0; nt < 4; nt++)
            ob[rl * 64 + nt * 16 + lr] = f2bf(acc[nt][r] * di);
    }
    __syncthreads();
    const unsigned int* ob32 = (const unsigned int*)ob;
    for (int i = t; i < 128 * 32; i += 512) {
        int rl = i >> 5, cu = i & 31;
        int grow = rowbase + rl;
        if (grow < n) h2[(size_t)grow * 32 + cu] = ob32[rl * 32 + cu];
    }
}

// ------------ aggregation 2 -> output (bf16 gather, fp32 out) ------------

__global__ __launch_bounds__(64) void agg2_k(const unsigned short* __restrict__ hs,  // bf16, 64/row
                                             const float* __restrict__ dinv,
                                             const int* __restrict__ rowptr,
                                             const int* __restrict__ srcs,
                                             const float* __restrict__ b2,
                                             float* __restrict__ out, int n) {
    int nd = blockIdx.x;
    int f = threadIdx.x;
    float di = dinv[nd];
    float acc = bf2f(hs[(size_t)nd * F2 + f]);
    int e = rowptr[nd], e1 = rowptr[nd + 1];
    for (; e + 8 <= e1; e += 8) {
        int s0 = srcs[e],     s1 = srcs[e + 1], s2 = srcs[e + 2], s3 = srcs[e + 3];
        int s4 = srcs[e + 4], s5 = srcs[e + 5], s6 = srcs[e + 6], s7 = srcs[e + 7];
        float h0 = bf2f(hs[(size_t)s0 * F2 + f]);
        float h1 = bf2f(hs[(size_t)s1 * F2 + f]);
        float h2 = bf2f(hs[(size_t)s2 * F2 + f]);
        float h3 = bf2f(hs[(size_t)s3 * F2 + f]);
        float h4 = bf2f(hs[(size_t)s4 * F2 + f]);
        float h5 = bf2f(hs[(size_t)s5 * F2 + f]);
        float h6 = bf2f(hs[(size_t)s6 * F2 + f]);
        float h7 = bf2f(hs[(size_t)s7 * F2 + f]);
        acc += h0 + h1 + h2 + h3;
        acc += h4 + h5 + h6 + h7;
    }
    for (; e < e1; e++)
        acc += bf2f(hs[(size_t)srcs[e] * F2 + f]);
    float o = fmaf(acc, di, b2[f]);
    __builtin_nontemporal_store(o, out + (size_t)nd * F2 + f);
}

// ---------------- launch ----------------

extern "C" void kernel_launch(void* const* d_in, const int* in_sizes, int n_in,
                              void* d_out, int out_size, void* d_ws, size_t ws_size,
                              hipStream_t stream) {
    const float* x       = (const float*)d_in[0];
    const int*   ei      = (const int*)d_in[1];
    const float* W1      = (const float*)d_in[2];
    const float* b1      = (const float*)d_in[3];
    const float* W2      = (const float*)d_in[4];
    const float* b2      = (const float*)d_in[5];
    const float* gamma   = (const float*)d_in[6];
    const float* beta    = (const float*)d_in[7];
    const float* prelu_a = (const float*)d_in[8];

    const int N = in_sizes[0] / DIN;
    const int E = in_sizes[1] / 2;
    const int* src = ei;
    const int* dst = ei + E;
    const int NBUCK = (N + NODE_BMASK) >> NODE_BSHIFT;  // 391 for N=100000

    char* p = (char*)d_ws;
    size_t off = 0;
    auto take = [&](size_t bytes) -> char* {
        char* r = p + off;
        off = (off + bytes + 255) & ~(size_t)255;
        return r;
    };
    int*            bucketcnt  = (int*)take(512 * 4);
    int*            bucketbase = (int*)take(513 * 4);
    int*            bucketcur  = (int*)take(512 * 4);
    float*          dinv       = (float*)take((size_t)N * 4);
    int*            rowptr     = (int*)take((size_t)(N + 1) * 4);
    int*            srcsorted  = (int*)take((size_t)E * 4);
    int2*           pairs      = (int2*)take((size_t)E * 8);
    double*         bnacc      = (double*)take(2 * F1 * 8);
    unsigned int*   h          = (unsigned int*)take((size_t)N * 64 * 4);  // bf16 h' (128 feats)
    float*          z          = (float*)take((size_t)N * F1 * 4);
    unsigned int*   h2         = h;   // h dead after agg1; bf16 h2' (64 feats)
    float*          out        = (float*)d_out;

    hipMemsetAsync(bucketcnt, 0, 512 * 4, stream);
    hipMemsetAsync(bnacc, 0, 2 * F1 * 8, stream);

    const int eb = (E + CHUNK - 1) / CHUNK;

    hist_k<<<eb, 256, 0, stream>>>(dst, bucketcnt, E, NBUCK);
    bscan_k<<<1, 512, 0, stream>>>(bucketcnt, bucketbase, bucketcur, rowptr, NBUCK, N, E);
    binpass_k<<<eb, 256, 0, stream>>>(src, dst, bucketcur, pairs, E);
    bucket_k<<<NBUCK, 256, 0, stream>>>(pairs, bucketbase, dinv, rowptr, srcsorted, N);

    gemm1_k<<<(N + 127) / 128, 512, 0, stream>>>(x, W1, dinv, h, N);
    agg1_k<<<N, 64, 0, stream>>>(h, dinv, rowptr, srcsorted, b1, z, N);
    bnstats_k<<<512, F1, 0, stream>>>(z, bnacc, N);
    gemm2_k<<<(N + 127) / 128, 512, 0, stream>>>(z, W2, bnacc, gamma, beta, prelu_a, dinv, h2, N);
    agg2_k<<<N, F2, 0, stream>>>((const unsigned short*)h2, dinv, rowptr, srcsorted, b2, out, N);
}

// Round 3
// 352.915 us; speedup vs baseline: 1.2009x; 1.1952x over previous
//
#include <hip/hip_runtime.h>

// GCN forward: conv1(GEMM + sym-norm agg) -> BN -> PReLU -> conv2(GEMM + agg)
// N=100000, E=1600000, DIN=128, 2H=128, H=64. fp32 in/out.
//
// R6 changes vs R5 (422 us):
//  - bnstats_k was the #1 dispatch (89 us, 295 GB/s, VALUBusy 1%): 128 scalar
//    4B loads/block-iter = latency-bound. Rewritten: 1024x256, float4 loads
//    (8 row-lanes x 32 f4-cols), fp32 partials -> LDS reduce -> 128 feats/block,
//    atomics to 4 interleaved bnacc copies (contention 1024 -> 256/address).
//    gemm2's fused bnfinal sums the 4 copies.
// R5/R4 (vs R3 424 us): MFMA split-precision GEMMs, fused bnfinal, dinv
// pre-scaling in GEMM epilogues, 8-deep agg unroll, NT z/out stores.

#define DIN 128
#define F1  128   // 2H
#define F2  64    // H
#define BN_EPS 1e-5f
#define NODE_BSHIFT 8          // 256 nodes per bucket
#define NODE_BMASK  255
#define CHUNK 8192             // edges per binpass block

typedef __attribute__((ext_vector_type(8))) short bf16x8;
typedef __attribute__((ext_vector_type(4))) float f32x4;
typedef __attribute__((ext_vector_type(2))) float f32x2;

__device__ __forceinline__ unsigned short f2bf(float f) {
    unsigned int u = __float_as_uint(f);
    u = u + 0x7fffu + ((u >> 16) & 1u);   // RNE
    return (unsigned short)(u >> 16);
}
__device__ __forceinline__ float bf2f(unsigned short u) { return __uint_as_float((unsigned int)u << 16); }
__device__ __forceinline__ float bf_lo(unsigned int v) { return __uint_as_float(v << 16); }
__device__ __forceinline__ float bf_hi(unsigned int v) { return __uint_as_float(v & 0xffff0000u); }

// ---------------- graph build (unchanged from R3) ----------------

__global__ __launch_bounds__(256) void hist_k(const int* __restrict__ dst,
                                              int* __restrict__ bucketcnt,
                                              int e, int nbuck) {
    __shared__ int lh[512];
    int t = threadIdx.x;
    for (int i = t; i < 512; i += 256) lh[i] = 0;
    __syncthreads();
    int base = blockIdx.x * CHUNK;
    int end = base + CHUNK; if (end > e) end = e;
    for (int i = base + t; i < end; i += 256)
        atomicAdd(&lh[dst[i] >> NODE_BSHIFT], 1);
    __syncthreads();
    for (int b = t; b < nbuck; b += 256) {
        int v = lh[b];
        if (v) atomicAdd(&bucketcnt[b], v);
    }
}

__global__ __launch_bounds__(512) void bscan_k(const int* __restrict__ bucketcnt,
                                               int* __restrict__ bucketbase,
                                               int* __restrict__ bucketcur,
                                               int* __restrict__ rowptr,
                                               int nbuck, int n, int e) {
    __shared__ int s[512];
    int t = threadIdx.x;
    int orig = (t < nbuck) ? bucketcnt[t] : 0;
    s[t] = orig;
    __syncthreads();
    int run = orig;
    for (int ofs = 1; ofs < 512; ofs <<= 1) {
        int y = (t >= ofs) ? s[t - ofs] : 0;
        __syncthreads();
        run += y;
        s[t] = run;
        __syncthreads();
    }
    if (t < nbuck) {
        int excl = run - orig;
        bucketbase[t] = excl;
        bucketcur[t] = excl;
    }
    if (t == 0) {
        bucketbase[nbuck] = e;
        rowptr[n] = e;
    }
}

__global__ __launch_bounds__(256) void binpass_k(const int* __restrict__ src,
                                                 const int* __restrict__ dst,
                                                 int* __restrict__ bucketcur,
                                                 int2* __restrict__ pairs, int e) {
    __shared__ int lh[512], lbase[512], lrank[512];
    int t = threadIdx.x;
    for (int i = t; i < 512; i += 256) { lh[i] = 0; lrank[i] = 0; }
    __syncthreads();
    int base = blockIdx.x * CHUNK;
    int end = base + CHUNK; if (end > e) end = e;
    for (int i = base + t; i < end; i += 256)
        atomicAdd(&lh[dst[i] >> NODE_BSHIFT], 1);
    __syncthreads();
    for (int b = t; b < 512; b += 256) {
        int v = lh[b];
        lbase[b] = v ? atomicAdd(&bucketcur[b], v) : 0;
    }
    __syncthreads();
    for (int i = base + t; i < end; i += 256) {
        int sv = src[i], dv = dst[i];
        int b = dv >> NODE_BSHIFT;
        int r = atomicAdd(&lrank[b], 1);
        pairs[lbase[b] + r] = make_int2(sv, dv);
    }
}

__global__ __launch_bounds__(256) void bucket_k(const int2* __restrict__ pairs,
                                                const int* __restrict__ bucketbase,
                                                float* __restrict__ dinv,
                                                int* __restrict__ rowptr,
                                                int* __restrict__ srcsorted, int n) {
    __shared__ int lh[256], loff[256], lrank[256];
    int b = blockIdx.x, t = threadIdx.x;
    int e0 = bucketbase[b], e1 = bucketbase[b + 1];
    lh[t] = 0;
    lrank[t] = 0;
    __syncthreads();
    for (int i = e0 + t; i < e1; i += 256)
        atomicAdd(&lh[pairs[i].y & NODE_BMASK], 1);
    __syncthreads();
    int deg = lh[t];
    int run = deg;
    for (int ofs = 1; ofs < 256; ofs <<= 1) {
        int y = (t >= ofs) ? lh[t - ofs] : 0;
        __syncthreads();
        run += y;
        lh[t] = run;
        __syncthreads();
    }
    loff[t] = run - deg;
    int node = (b << NODE_BSHIFT) + t;
    if (node < n) {
        dinv[node] = rsqrtf((float)(deg + 1));   // +1 self-loop
        rowptr[node] = e0 + (run - deg);
    }
    __syncthreads();
    for (int i = e0 + t; i < e1; i += 256) {
        int2 p = pairs[i];
        int lo = p.y & NODE_BMASK;
        int r = atomicAdd(&lrank[lo], 1);
        srcsorted[e0 + loff[lo] + r] = p.x;
    }
}

// ---- GEMM1 (MFMA): h'(bf16) = dinv * (x @ W1), split precision ----
// 128 rows/block, 512 threads (8 waves of 16 rows x 128 cols).

__global__ __launch_bounds__(512) void gemm1_k(const float* __restrict__ x,
                                               const float* __restrict__ W,
                                               const float* __restrict__ dinv,
                                               unsigned int* __restrict__ h, int n) {
    __shared__ unsigned short wh[128 * 128];   // W^T hi, [col][k], 16B-chunk XOR swizzle
    __shared__ unsigned short wl[128 * 128];   // W^T lo
    int t = threadIdx.x;
    // stage W1 [k=128][c=128] fp32 -> swizzled transposed bf16 hi/lo
    for (int i4 = t; i4 < 128 * 32; i4 += 512) {
        int k = i4 >> 5;
        int c0 = (i4 & 31) * 4;
        float4 v = ((const float4*)W)[i4];
        float vv[4] = {v.x, v.y, v.z, v.w};
#pragma unroll
        for (int j = 0; j < 4; j++) {
            int c = c0 + j;
            unsigned short hi = f2bf(vv[j]);
            unsigned short lo = f2bf(vv[j] - bf2f(hi));
            int addr = c * 128 + ((((k >> 3) ^ (c & 15))) << 3) + (k & 7);
            wh[addr] = hi;
            wl[addr] = lo;
        }
    }
    __syncthreads();

    int w = t >> 6, l = t & 63;
    int lr = l & 15, lg = l >> 4;
    int rowbase = blockIdx.x * 128;
    int arow = rowbase + w * 16 + lr;
    if (arow >= n) arow = n - 1;

    f32x4 acc[8];
#pragma unroll
    for (int nt = 0; nt < 8; nt++) acc[nt] = (f32x4)(0.0f);

#pragma unroll
    for (int ks = 0; ks < 4; ks++) {
        const float4* ap = (const float4*)(x + (size_t)arow * 128 + ks * 32 + lg * 8);
        float4 v0 = ap[0], v1 = ap[1];
        float vv[8] = {v0.x, v0.y, v0.z, v0.w, v1.x, v1.y, v1.z, v1.w};
        bf16x8 ah, al;
#pragma unroll
        for (int j = 0; j < 8; j++) {
            unsigned short hi = f2bf(vv[j]);
            ah[j] = (short)hi;
            al[j] = (short)f2bf(vv[j] - bf2f(hi));
        }
#pragma unroll
        for (int nt = 0; nt < 8; nt++) {
            int ao = (nt * 16 + lr) * 128 + (((4 * ks + lg) ^ lr) << 3);
            bf16x8 bh = *(const bf16x8*)&wh[ao];
            bf16x8 bl = *(const bf16x8*)&wl[ao];
            acc[nt] = __builtin_amdgcn_mfma_f32_16x16x32_bf16(ah, bh, acc[nt], 0, 0, 0);
            acc[nt] = __builtin_amdgcn_mfma_f32_16x16x32_bf16(al, bh, acc[nt], 0, 0, 0);
            acc[nt] = __builtin_amdgcn_mfma_f32_16x16x32_bf16(ah, bl, acc[nt], 0, 0, 0);
        }
    }
    __syncthreads();                       // all waves done reading W
    unsigned short* ob = wh;               // reuse as [128][128] bf16 bounce
#pragma unroll
    for (int r = 0; r < 4; r++) {
        int rl = w * 16 + lg * 4 + r;      // C row = (lane>>4)*4 + reg
        int grow = rowbase + rl;
        float di = dinv[grow < n ? grow : 0];
#pragma unroll
        for (int nt = 0; nt < 8; nt++)
            ob[rl * 128 + nt * 16 + lr] = f2bf(acc[nt][r] * di);
    }
    __syncthreads();
    const unsigned int* ob32 = (const unsigned int*)ob;
    for (int i = t; i < 128 * 64; i += 512) {
        int rl = i >> 6, cu = i & 63;
        int grow = rowbase + rl;
        if (grow < n) h[(size_t)grow * 64 + cu] = ob32[rl * 64 + cu];
    }
}

// -------- aggregation 1: z = dinv_d * (sum h'_s + h'_d) + b1 --------

__global__ __launch_bounds__(64) void agg1_k(const unsigned int* __restrict__ h,  // bf16x2, 64/row
                                             const float* __restrict__ dinv,
                                             const int* __restrict__ rowptr,
                                             const int* __restrict__ srcs,
                                             const float* __restrict__ b1,
                                             float* __restrict__ z, int n) {
    int nd = blockIdx.x;
    int f = threadIdx.x;  // bf16-pair index, 0..63
    float di = dinv[nd];
    unsigned int sv = h[(size_t)nd * 64 + f];
    float ax = bf_lo(sv);
    float ay = bf_hi(sv);
    int e = rowptr[nd], e1 = rowptr[nd + 1];
    for (; e + 8 <= e1; e += 8) {
        int s0 = srcs[e],     s1 = srcs[e + 1], s2 = srcs[e + 2], s3 = srcs[e + 3];
        int s4 = srcs[e + 4], s5 = srcs[e + 5], s6 = srcs[e + 6], s7 = srcs[e + 7];
        unsigned int v0 = h[(size_t)s0 * 64 + f];
        unsigned int v1 = h[(size_t)s1 * 64 + f];
        unsigned int v2 = h[(size_t)s2 * 64 + f];
        unsigned int v3 = h[(size_t)s3 * 64 + f];
        unsigned int v4 = h[(size_t)s4 * 64 + f];
        unsigned int v5 = h[(size_t)s5 * 64 + f];
        unsigned int v6 = h[(size_t)s6 * 64 + f];
        unsigned int v7 = h[(size_t)s7 * 64 + f];
        ax += bf_lo(v0) + bf_lo(v1) + bf_lo(v2) + bf_lo(v3);
        ay += bf_hi(v0) + bf_hi(v1) + bf_hi(v2) + bf_hi(v3);
        ax += bf_lo(v4) + bf_lo(v5) + bf_lo(v6) + bf_lo(v7);
        ay += bf_hi(v4) + bf_hi(v5) + bf_hi(v6) + bf_hi(v7);
    }
    for (; e < e1; e++) {
        unsigned int v = h[(size_t)srcs[e] * 64 + f];
        ax += bf_lo(v);
        ay += bf_hi(v);
    }
    float2 bb = ((const float2*)b1)[f];
    f32x2 o;
    o.x = fmaf(ax, di, bb.x);
    o.y = fmaf(ay, di, bb.y);
    __builtin_nontemporal_store(o, (f32x2*)z + (size_t)nd * 64 + f);
}

// ---------------- BatchNorm stats ----------------
// 1024 blocks x 256 threads: 8 row-lanes x 32 float4-cols, LDS reduce,
// atomics to 4 interleaved bnacc copies (per-address contention 256).

__global__ __launch_bounds__(256) void bnstats_k(const float* __restrict__ z,
                                                 double* __restrict__ bnacc, int n) {
    __shared__ float reds[8][128];
    __shared__ float redq[8][128];
    int t = threadIdx.x;
    int q = t >> 5;          // row lane 0..7
    int c = t & 31;          // float4 column
    const float4* z4 = (const float4*)z;
    float4 s = make_float4(0.f, 0.f, 0.f, 0.f);
    float4 sq = make_float4(0.f, 0.f, 0.f, 0.f);
    int stride = gridDim.x * 8;
#pragma unroll 2
    for (int r = blockIdx.x * 8 + q; r < n; r += stride) {
        float4 v = z4[(size_t)r * 32 + c];
        s.x += v.x; s.y += v.y; s.z += v.z; s.w += v.w;
        sq.x = fmaf(v.x, v.x, sq.x);
        sq.y = fmaf(v.y, v.y, sq.y);
        sq.z = fmaf(v.z, v.z, sq.z);
        sq.w = fmaf(v.w, v.w, sq.w);
    }
    *(float4*)&reds[q][c * 4] = s;
    *(float4*)&redq[q][c * 4] = sq;
    __syncthreads();
    if (t < 128) {
        float ssum = 0.f, qsum = 0.f;
#pragma unroll
        for (int i = 0; i < 8; i++) {
            ssum += reds[i][t];
            qsum += redq[i][t];
        }
        int copy = (blockIdx.x & 3) * 256;
        atomicAdd(&bnacc[copy + t], (double)ssum);
        atomicAdd(&bnacc[copy + 128 + t], (double)qsum);
    }
}

// ---- GEMM2 (MFMA): h2'(bf16) = dinv * (prelu(bn(z)) @ W2), bnfinal fused ----
// 128 rows/block, 512 threads (8 waves of 16 rows x 64 cols).

__global__ __launch_bounds__(512) void gemm2_k(const float* __restrict__ z,
                                               const float* __restrict__ W,      // [128][64]
                                               const double* __restrict__ bnacc, // 4 copies x 256
                                               const float* __restrict__ gamma,
                                               const float* __restrict__ beta,
                                               const float* __restrict__ prelu_a,
                                               const float* __restrict__ dinv,
                                               unsigned int* __restrict__ h2, int n) {
    __shared__ unsigned short wh[64 * 128];
    __shared__ unsigned short wl[64 * 128];
    __shared__ float lsc[128], lsh[128];
    int t = threadIdx.x;
    for (int i4 = t; i4 < 128 * 16; i4 += 512) {
        int k = i4 >> 4;
        int c0 = (i4 & 15) * 4;
        float4 v = ((const float4*)W)[i4];
        float vv[4] = {v.x, v.y, v.z, v.w};
#pragma unroll
        for (int j = 0; j < 4; j++) {
            int c = c0 + j;
            unsigned short hi = f2bf(vv[j]);
            unsigned short lo = f2bf(vv[j] - bf2f(hi));
            int addr = c * 128 + ((((k >> 3) ^ (c & 15))) << 3) + (k & 7);
            wh[addr] = hi;
            wl[addr] = lo;
        }
    }
    if (t < 128) {   // fused bnfinal (sum the 4 interleaved copies)
        double sm = 0.0, qq = 0.0;
#pragma unroll
        for (int cpy = 0; cpy < 4; cpy++) {
            sm += bnacc[cpy * 256 + t];
            qq += bnacc[cpy * 256 + 128 + t];
        }
        double mean = sm / n;
        double var = qq / n - mean * mean;
        float sc = gamma[t] * rsqrtf((float)var + BN_EPS);
        lsc[t] = sc;
        lsh[t] = beta[t] - (float)mean * sc;
    }
    __syncthreads();

    float pa = prelu_a[0];
    int w = t >> 6, l = t & 63;
    int lr = l & 15, lg = l >> 4;
    int rowbase = blockIdx.x * 128;
    int arow = rowbase + w * 16 + lr;
    if (arow >= n) arow = n - 1;

    f32x4 acc[4];
#pragma unroll
    for (int nt = 0; nt < 4; nt++) acc[nt] = (f32x4)(0.0f);

#pragma unroll
    for (int ks = 0; ks < 4; ks++) {
        const float4* ap = (const float4*)(z + (size_t)arow * 128 + ks * 32 + lg * 8);
        float4 v0 = ap[0], v1 = ap[1];
        const float4* sc4 = (const float4*)&lsc[ks * 32 + lg * 8];
        const float4* sh4 = (const float4*)&lsh[ks * 32 + lg * 8];
        float4 s0 = sc4[0], s1 = sc4[1];
        float4 t0 = sh4[0], t1 = sh4[1];
        float vv[8];
        vv[0] = fmaf(v0.x, s0.x, t0.x); vv[1] = fmaf(v0.y, s0.y, t0.y);
        vv[2] = fmaf(v0.z, s0.z, t0.z); vv[3] = fmaf(v0.w, s0.w, t0.w);
        vv[4] = fmaf(v1.x, s1.x, t1.x); vv[5] = fmaf(v1.y, s1.y, t1.y);
        vv[6] = fmaf(v1.z, s1.z, t1.z); vv[7] = fmaf(v1.w, s1.w, t1.w);
        bf16x8 ah, al;
#pragma unroll
        for (int j = 0; j < 8; j++) {
            float y = vv[j] >= 0.f ? vv[j] : pa * vv[j];
            unsigned short hi = f2bf(y);
            ah[j] = (short)hi;
            al[j] = (short)f2bf(y - bf2f(hi));
        }
#pragma unroll
        for (int nt = 0; nt < 4; nt++) {
            int ao = (nt * 16 + lr) * 128 + (((4 * ks + lg) ^ lr) << 3);
            bf16x8 bh = *(const bf16x8*)&wh[ao];
            bf16x8 bl = *(const bf16x8*)&wl[ao];
            acc[nt] = __builtin_amdgcn_mfma_f32_16x16x32_bf16(ah, bh, acc[nt], 0, 0, 0);
            acc[nt] = __builtin_amdgcn_mfma_f32_16x16x32_bf16(al, bh, acc[nt], 0, 0, 0);
            acc[nt] = __builtin_amdgcn_mfma_f32_16x16x32_bf16(ah, bl, acc[nt], 0, 0, 0);
        }
    }
    __syncthreads();
    unsigned short* ob = wh;   // reuse as [128][64] bf16 bounce
#pragma unroll
    for (int r = 0; r < 4; r++) {
        int rl = w * 16 + lg * 4 + r;
        int grow = rowbase + rl;
        float di = dinv[grow < n ? grow : 0];
#pragma unroll
        for (int nt = 0; nt < 4; nt++)
            ob[rl * 64 + nt * 16 + lr] = f2bf(acc[nt][r] * di);
    }
    __syncthreads();
    const unsigned int* ob32 = (const unsigned int*)ob;
    for (int i = t; i < 128 * 32; i += 512) {
        int rl = i >> 5, cu = i & 31;
        int grow = rowbase + rl;
        if (grow < n) h2[(size_t)grow * 32 + cu] = ob32[rl * 32 + cu];
    }
}

// ------------ aggregation 2 -> output (bf16 gather, fp32 out) ------------

__global__ __launch_bounds__(64) void agg2_k(const unsigned short* __restrict__ hs,  // bf16, 64/row
                                             const float* __restrict__ dinv,
                                             const int* __restrict__ rowptr,
                                             const int* __restrict__ srcs,
                                             const float* __restrict__ b2,
                                             float* __restrict__ out, int n) {
    int nd = blockIdx.x;
    int f = threadIdx.x;
    float di = dinv[nd];
    float acc = bf2f(hs[(size_t)nd * F2 + f]);
    int e = rowptr[nd], e1 = rowptr[nd + 1];
    for (; e + 8 <= e1; e += 8) {
        int s0 = srcs[e],     s1 = srcs[e + 1], s2 = srcs[e + 2], s3 = srcs[e + 3];
        int s4 = srcs[e + 4], s5 = srcs[e + 5], s6 = srcs[e + 6], s7 = srcs[e + 7];
        float h0 = bf2f(hs[(size_t)s0 * F2 + f]);
        float h1 = bf2f(hs[(size_t)s1 * F2 + f]);
        float h2 = bf2f(hs[(size_t)s2 * F2 + f]);
        float h3 = bf2f(hs[(size_t)s3 * F2 + f]);
        float h4 = bf2f(hs[(size_t)s4 * F2 + f]);
        float h5 = bf2f(hs[(size_t)s5 * F2 + f]);
        float h6 = bf2f(hs[(size_t)s6 * F2 + f]);
        float h7 = bf2f(hs[(size_t)s7 * F2 + f]);
        acc += h0 + h1 + h2 + h3;
        acc += h4 + h5 + h6 + h7;
    }
    for (; e < e1; e++)
        acc += bf2f(hs[(size_t)srcs[e] * F2 + f]);
    float o = fmaf(acc, di, b2[f]);
    __builtin_nontemporal_store(o, out + (size_t)nd * F2 + f);
}

// ---------------- launch ----------------

extern "C" void kernel_launch(void* const* d_in, const int* in_sizes, int n_in,
                              void* d_out, int out_size, void* d_ws, size_t ws_size,
                              hipStream_t stream) {
    const float* x       = (const float*)d_in[0];
    const int*   ei      = (const int*)d_in[1];
    const float* W1      = (const float*)d_in[2];
    const float* b1      = (const float*)d_in[3];
    const float* W2      = (const float*)d_in[4];
    const float* b2      = (const float*)d_in[5];
    const float* gamma   = (const float*)d_in[6];
    const float* beta    = (const float*)d_in[7];
    const float* prelu_a = (const float*)d_in[8];

    const int N = in_sizes[0] / DIN;
    const int E = in_sizes[1] / 2;
    const int* src = ei;
    const int* dst = ei + E;
    const int NBUCK = (N + NODE_BMASK) >> NODE_BSHIFT;  // 391 for N=100000

    char* p = (char*)d_ws;
    size_t off = 0;
    auto take = [&](size_t bytes) -> char* {
        char* r = p + off;
        off = (off + bytes + 255) & ~(size_t)255;
        return r;
    };
    int*            bucketcnt  = (int*)take(512 * 4);
    int*            bucketbase = (int*)take(513 * 4);
    int*            bucketcur  = (int*)take(512 * 4);
    float*          dinv       = (float*)take((size_t)N * 4);
    int*            rowptr     = (int*)take((size_t)(N + 1) * 4);
    int*            srcsorted  = (int*)take((size_t)E * 4);
    int2*           pairs      = (int2*)take((size_t)E * 8);
    double*         bnacc      = (double*)take(4 * 256 * 8);   // 4 interleaved copies
    unsigned int*   h          = (unsigned int*)take((size_t)N * 64 * 4);  // bf16 h' (128 feats)
    float*          z          = (float*)take((size_t)N * F1 * 4);
    unsigned int*   h2         = h;   // h dead after agg1; bf16 h2' (64 feats)
    float*          out        = (float*)d_out;

    hipMemsetAsync(bucketcnt, 0, 512 * 4, stream);
    hipMemsetAsync(bnacc, 0, 4 * 256 * 8, stream);

    const int eb = (E + CHUNK - 1) / CHUNK;

    hist_k<<<eb, 256, 0, stream>>>(dst, bucketcnt, E, NBUCK);
    bscan_k<<<1, 512, 0, stream>>>(bucketcnt, bucketbase, bucketcur, rowptr, NBUCK, N, E);
    binpass_k<<<eb, 256, 0, stream>>>(src, dst, bucketcur, pairs, E);
    bucket_k<<<NBUCK, 256, 0, stream>>>(pairs, bucketbase, dinv, rowptr, srcsorted, N);

    gemm1_k<<<(N + 127) / 128, 512, 0, stream>>>(x, W1, dinv, h, N);
    agg1_k<<<N, 64, 0, stream>>>(h, dinv, rowptr, srcsorted, b1, z, N);
    bnstats_k<<<1024, 256, 0, stream>>>(z, bnacc, N);
    gemm2_k<<<(N + 127) / 128, 512, 0, stream>>>(z, W2, bnacc, gamma, beta, prelu_a, dinv, h2, N);
    agg2_k<<<N, F2, 0, stream>>>((const unsigned short*)h2, dinv, rowptr, srcsorted, b2, out, N);
}